// Round 4
// baseline (772.434 us; speedup 1.0000x reference)
//
#include <hip/hip_runtime.h>
#include <hip/hip_bf16.h>

#define S_LEN 4096
#define DMODEL 2048
#define NHEADS 16
#define HEADDIM 128

typedef __attribute__((ext_vector_type(8))) short bf16x8;
typedef __attribute__((ext_vector_type(4))) float f32x4;

__device__ __forceinline__ float bf2f(ushort u) {
  union { unsigned int i; float f; } x; x.i = ((unsigned int)u) << 16; return x.f;
}
__device__ __forceinline__ ushort f2bf(float f) {
  union { float f; unsigned int i; } x; x.f = f;
  unsigned int u = x.i;
  unsigned int r = u + 0x7fffu + ((u >> 16) & 1u);
  return (ushort)(r >> 16);
}
__device__ __forceinline__ void splitf(float f, ushort& h, ushort& l) {
  unsigned int u = __float_as_uint(f);
  h = (ushort)(u >> 16);
  l = f2bf(f - __uint_as_float(u & 0xffff0000u));
}

__device__ __forceinline__ void gload16(const ushort* g, ushort* l) {
  __builtin_amdgcn_global_load_lds(
      (const __attribute__((address_space(1))) unsigned int*)g,
      (__attribute__((address_space(3))) unsigned int*)l, 16, 0, 0);
}

// ---------------- RoPE cos/sin table: [S][64] each ----------------
__global__ __launch_bounds__(256) void rope_table_kernel(float* __restrict__ cosT,
                                                         float* __restrict__ sinT) {
  int idx = blockIdx.x * 256 + threadIdx.x;  // S*64
  int t = idx >> 6, j = idx & 63;
  float expo = (float)(2 * j) / 128.0f;
  float inv = 1.0f / powf(10000.0f, expo);
  float f = (float)t * inv;
  cosT[idx] = cosf(f);
  sinT[idx] = sinf(f);
}

// ---------------- fp32 -> bf16 hi/lo split ----------------
__global__ __launch_bounds__(256) void split_kernel(const float* __restrict__ in,
                                                    ushort* __restrict__ hi,
                                                    ushort* __restrict__ lo) {
  int i = (blockIdx.x * 256 + threadIdx.x) * 4;
  float4 v = *reinterpret_cast<const float4*>(&in[i]);
  ushort4 h, l;
  splitf(v.x, h.x, l.x);
  splitf(v.y, h.y, l.y);
  splitf(v.z, h.z, l.z);
  splitf(v.w, h.w, l.w);
  *reinterpret_cast<ushort4*>(&hi[i]) = h;
  *reinterpret_cast<ushort4*>(&lo[i]) = l;
}

// ---------------- 3-term bf16 GEMM: C = (Ah+Al) * (Bh+Bl)^T (drop Al*Bl) ----------------
__global__ __launch_bounds__(256) void gemm3(const ushort* __restrict__ Ah_,
                                             const ushort* __restrict__ Al_,
                                             const ushort* __restrict__ Bh_,
                                             const ushort* __restrict__ Bl_,
                                             void* __restrict__ Cout,
                                             int M, int N, int K, int f32out) {
  __shared__ __align__(16) ushort sAh[128 * 32], sAl[128 * 32], sBh[128 * 32], sBl[128 * 32];
  const int tid = threadIdx.x;
  const int wave = tid >> 6, lane = tid & 63;
  const int lg = lane >> 4, lm = lane & 15;
  const int nwg = gridDim.x * gridDim.y;
  const int id = blockIdx.y * gridDim.x + blockIdx.x;
  const int cpx = nwg >> 3;
  const int swz = (id & 7) * cpx + (id >> 3);
  const int nbx = N >> 7;
  const int m0 = (swz / nbx) * 128, n0 = (swz % nbx) * 128;
  const int wm = (wave >> 1) * 64, wn = (wave & 1) * 64;
  f32x4 acc[4][4] = {};

  for (int k0 = 0; k0 < K; k0 += 32) {
    __syncthreads();
#pragma unroll
    for (int t = 0; t < 2; ++t) {
      int r = wave * 32 + t * 16 + (lane >> 2);
      int ca = (lane & 3) ^ ((r >> 1) & 3);
      size_t ga = (size_t)(m0 + r) * K + k0 + ca * 8;
      size_t gb = (size_t)(n0 + r) * K + k0 + ca * 8;
      int lb = (wave * 32 + t * 16) * 32;
      gload16(&Ah_[ga], &sAh[lb]);
      gload16(&Al_[ga], &sAl[lb]);
      gload16(&Bh_[gb], &sBh[lb]);
      gload16(&Bl_[gb], &sBl[lb]);
    }
    __syncthreads();
    bf16x8 ah[4], al[4], bh[4], bl[4];
#pragma unroll
    for (int t = 0; t < 4; ++t) {
      int Ra = wm + t * 16 + lm;
      int Rb = wn + t * 16 + lm;
      int ca = (lg ^ ((Ra >> 1) & 3)) * 8;
      int cb = (lg ^ ((Rb >> 1) & 3)) * 8;
      ah[t] = *reinterpret_cast<const bf16x8*>(&sAh[Ra * 32 + ca]);
      al[t] = *reinterpret_cast<const bf16x8*>(&sAl[Ra * 32 + ca]);
      bh[t] = *reinterpret_cast<const bf16x8*>(&sBh[Rb * 32 + cb]);
      bl[t] = *reinterpret_cast<const bf16x8*>(&sBl[Rb * 32 + cb]);
    }
#pragma unroll
    for (int mi = 0; mi < 4; ++mi)
#pragma unroll
      for (int ni = 0; ni < 4; ++ni) {
        acc[mi][ni] = __builtin_amdgcn_mfma_f32_16x16x32_bf16(ah[mi], bh[ni], acc[mi][ni], 0, 0, 0);
        acc[mi][ni] = __builtin_amdgcn_mfma_f32_16x16x32_bf16(ah[mi], bl[ni], acc[mi][ni], 0, 0, 0);
        acc[mi][ni] = __builtin_amdgcn_mfma_f32_16x16x32_bf16(al[mi], bh[ni], acc[mi][ni], 0, 0, 0);
      }
  }
  if (f32out) {
    float* C = (float*)Cout;
#pragma unroll
    for (int mi = 0; mi < 4; ++mi)
#pragma unroll
      for (int ni = 0; ni < 4; ++ni)
#pragma unroll
        for (int j = 0; j < 4; ++j) {
          int row = m0 + wm + mi * 16 + lg * 4 + j;
          int col = n0 + wn + ni * 16 + lm;
          C[(size_t)row * N + col] = acc[mi][ni][j];
        }
  } else {
    ushort* C = (ushort*)Cout;
#pragma unroll
    for (int mi = 0; mi < 4; ++mi)
#pragma unroll
      for (int ni = 0; ni < 4; ++ni)
#pragma unroll
        for (int j = 0; j < 4; ++j) {
          int row = m0 + wm + mi * 16 + lg * 4 + j;
          int col = n0 + wn + ni * 16 + lm;
          C[(size_t)row * N + col] = f2bf(acc[mi][ni][j]);
        }
  }
}

// ---------------- RoPE in-place on Q (scaled 1/sqrt(HD)) and K ----------------
__global__ __launch_bounds__(256) void rope2_kernel(ushort* __restrict__ Q,
                                                    ushort* __restrict__ K,
                                                    const int* __restrict__ pos,
                                                    const float* __restrict__ cosT,
                                                    const float* __restrict__ sinT) {
  int idx = blockIdx.x * 256 + threadIdx.x;  // S*1024 (pairs)
  int s = idx >> 10, dh = idx & 1023;
  int hh = dh >> 6, j = dh & 63;
  int p = pos[s];
  float cs = cosT[p * 64 + j], sn = sinT[p * 64 + j];
  size_t i1 = (size_t)s * DMODEL + hh * HEADDIM + j, i2 = i1 + 64;
  float q1 = bf2f(Q[i1]), q2 = bf2f(Q[i2]);
  float k1 = bf2f(K[i1]), k2 = bf2f(K[i2]);
  const float scl = 0.08838834764831845f;  // 1/sqrt(128)
  Q[i1] = f2bf((q1 * cs - q2 * sn) * scl);
  Q[i2] = f2bf((q2 * cs + q1 * sn) * scl);
  K[i1] = f2bf(k1 * cs - k2 * sn);
  K[i2] = f2bf(k2 * cs + k1 * sn);
}

// ---------------- V transpose: Vr [S][D] -> Vt [D][S] (bf16) ----------------
__global__ __launch_bounds__(256) void transpose_kernel(const ushort* __restrict__ Vr,
                                                        ushort* __restrict__ Vt) {
  __shared__ __align__(16) ushort tile[64 * 72];
  int tid = threadIdx.x;
  int s0 = blockIdx.x * 64, c0 = blockIdx.y * 64;
#pragma unroll
  for (int it = 0; it < 2; ++it) {
    int i = tid + it * 256;
    int r = i >> 3, c = i & 7;
    *reinterpret_cast<uint4*>(&tile[r * 72 + c * 8]) =
        *reinterpret_cast<const uint4*>(&Vr[(size_t)(s0 + r) * DMODEL + c0 + c * 8]);
  }
  __syncthreads();
#pragma unroll
  for (int it = 0; it < 2; ++it) {
    int i = tid + it * 256;
    int cr = i >> 3, sc = i & 7;
    ushort tmp[8];
#pragma unroll
    for (int j = 0; j < 8; ++j) tmp[j] = tile[(sc * 8 + j) * 72 + cr];
    *reinterpret_cast<uint4*>(&Vt[(size_t)(c0 + cr) * S_LEN + s0 + sc * 8]) =
        *reinterpret_cast<uint4*>(tmp);
  }
}

// ---------------- Flash attention v3: swapped QK^T + key permutation ----------------
// 8 waves, QBLK=128 (16 q-rows/wave), KBLK=64.
// QK^T computed as mfma(K, Q) -> lane (lg,lm) holds S[q=lm][key rho(nf*16+lg*4+j)]
// with rho(s) = 32*(nf&1) + 8*lg + 4*(nf>>1) + j  (s = nf*16 + lg*4 + j).
// K staged permuted: LDS row s holds key k0 + rho(s), i.e. global row r -> LDS row
// sigma(r) = 16*(2*((r>>2)&1) + (r>>5)) + 4*((r>>3)&3) + (r&3).   (rho(sigma(r)) == r)
// Then PV A-frag pa[kk][e] = p[((e>>2)<<1)|kk][e&3] -- static, no cross-lane, no Ps LDS.
#define KLD 136  // 128 + 8 pad (ushorts)
#define VLD 72   // 64 + 8

__global__ __launch_bounds__(512, 4) void flash3_kernel(const ushort* __restrict__ Q,
                                                        const ushort* __restrict__ Kb,
                                                        const ushort* __restrict__ Vt,
                                                        ushort* __restrict__ Oh,
                                                        ushort* __restrict__ Ol) {
  __shared__ __align__(16) ushort Kt[64 * KLD];
  __shared__ __align__(16) ushort Vs[HEADDIM * VLD];
  const int tid = threadIdx.x;
  const int wave = tid >> 6, lane = tid & 63;
  const int lg = lane >> 4, lm = lane & 15;
  const int id = blockIdx.y * gridDim.x + blockIdx.x;  // 0..511
  const int o = (id & 7) * 64 + (id >> 3);             // XCD swizzle (bijective: 512=8*64)
  const int h = o >> 5;
  const int q0 = (o & 31) * 128;
  const int qrow = q0 + wave * 16 + lm;

  bf16x8 qh[4];
#pragma unroll
  for (int kc = 0; kc < 4; ++kc)
    qh[kc] = *reinterpret_cast<const bf16x8*>(&Q[(size_t)qrow * DMODEL + h * HEADDIM + kc * 32 + lg * 8]);

  f32x4 oacc[8] = {};
  float mrun = -3.0e38f, osum = 0.0f;

  // staging registers (async-STAGE: issue early, write after barrier)
  uint4 kreg[2], vreg[2];
  const int sr = tid >> 4, scol = tid & 15;       // K: rows 0..31 (+32), 16 chunks
  const int sd = tid >> 3, sc2 = tid & 7;         // V: rows 0..63 (+64), 8 chunks
  // sigma for the two K rows this thread writes
  auto sigma = [](int r) {
    return 16 * (2 * ((r >> 2) & 1) + (r >> 5)) + 4 * ((r >> 3) & 3) + (r & 3);
  };
  const int ksig0 = sigma(sr), ksig1 = sigma(sr + 32);

  auto issue_loads = [&](int k0) {
    kreg[0] = *reinterpret_cast<const uint4*>(&Kb[(size_t)(k0 + sr) * DMODEL + h * HEADDIM + scol * 8]);
    kreg[1] = *reinterpret_cast<const uint4*>(&Kb[(size_t)(k0 + sr + 32) * DMODEL + h * HEADDIM + scol * 8]);
    vreg[0] = *reinterpret_cast<const uint4*>(&Vt[(size_t)(h * HEADDIM + sd) * S_LEN + k0 + sc2 * 8]);
    vreg[1] = *reinterpret_cast<const uint4*>(&Vt[(size_t)(h * HEADDIM + sd + 64) * S_LEN + k0 + sc2 * 8]);
  };
  auto write_lds = [&]() {
    *reinterpret_cast<uint4*>(&Kt[ksig0 * KLD + scol * 8]) = kreg[0];
    *reinterpret_cast<uint4*>(&Kt[ksig1 * KLD + scol * 8]) = kreg[1];
    *reinterpret_cast<uint4*>(&Vs[sd * VLD + sc2 * 8]) = vreg[0];
    *reinterpret_cast<uint4*>(&Vs[(sd + 64) * VLD + sc2 * 8]) = vreg[1];
  };

  issue_loads(0);
  write_lds();
  __syncthreads();

  for (int t = 0; t < S_LEN / 64; ++t) {
    if (t < S_LEN / 64 - 1) issue_loads((t + 1) * 64);

    // QK^T swapped: st[nf][j] = S[q=lm][key rho(nf*16+lg*4+j)]
    f32x4 st[4] = {};
#pragma unroll
    for (int nf = 0; nf < 4; ++nf)
#pragma unroll
      for (int kc = 0; kc < 4; ++kc) {
        bf16x8 kfrag = *reinterpret_cast<const bf16x8*>(&Kt[(nf * 16 + lm) * KLD + kc * 32 + lg * 8]);
        st[nf] = __builtin_amdgcn_mfma_f32_16x16x32_bf16(kfrag, qh[kc], st[nf], 0, 0, 0);
      }

    // in-lane row max for q = lm, then across the 4 lg-replicas
    float m16 = st[0][0];
#pragma unroll
    for (int nf = 0; nf < 4; ++nf)
#pragma unroll
      for (int j = 0; j < 4; ++j) m16 = fmaxf(m16, st[nf][j]);
    m16 = fmaxf(m16, __shfl_xor(m16, 16));
    m16 = fmaxf(m16, __shfl_xor(m16, 32));

    // defer-max rescale (wave-uniform branch)
    if (__any(m16 > mrun + 8.0f)) {
      float mn = fmaxf(mrun, m16);
      float scl = __expf(mrun - mn);
      mrun = mn;
      osum *= scl;
      float sj[4];
#pragma unroll
      for (int j = 0; j < 4; ++j) sj[j] = __shfl(scl, lg * 4 + j);
#pragma unroll
      for (int nb = 0; nb < 8; ++nb)
#pragma unroll
        for (int j = 0; j < 4; ++j) oacc[nb][j] *= sj[j];
    }

    // P = exp(S - m); in-lane sum
    float p[4][4];
    float rs = 0.0f;
#pragma unroll
    for (int nf = 0; nf < 4; ++nf)
#pragma unroll
      for (int j = 0; j < 4; ++j) {
        float pv = __expf(st[nf][j] - mrun);
        p[nf][j] = pv;
        rs += pv;
      }
    rs += __shfl_xor(rs, 16);
    rs += __shfl_xor(rs, 32);
    osum += rs;

    // pack to PV A-frags: pa[kk][e] = p[((e>>2)<<1)|kk][e&3]  (keys kk*32+8*lg+e)
    bf16x8 pa[2];
#pragma unroll
    for (int kk = 0; kk < 2; ++kk)
#pragma unroll
      for (int e = 0; e < 8; ++e)
        pa[kk][e] = (short)f2bf(p[((e >> 2) << 1) | kk][e & 3]);

    // PV
#pragma unroll
    for (int kk = 0; kk < 2; ++kk)
#pragma unroll
      for (int nb = 0; nb < 8; ++nb) {
        bf16x8 vfrag = *reinterpret_cast<const bf16x8*>(&Vs[(nb * 16 + lm) * VLD + kk * 32 + lg * 8]);
        oacc[nb] = __builtin_amdgcn_mfma_f32_16x16x32_bf16(pa[kk], vfrag, oacc[nb], 0, 0, 0);
      }

    __syncthreads();
    if (t < S_LEN / 64 - 1) write_lds();
    __syncthreads();
  }

  // epilogue: oacc rows are q = lg*4+j; osum is per q=lm -> redistribute
  float inv = 1.0f / osum;
  float linv[4];
#pragma unroll
  for (int j = 0; j < 4; ++j) linv[j] = __shfl(inv, lg * 4 + j);
#pragma unroll
  for (int nb = 0; nb < 8; ++nb)
#pragma unroll
    for (int j = 0; j < 4; ++j) {
      int row = q0 + wave * 16 + lg * 4 + j;
      int col = h * HEADDIM + nb * 16 + lm;
      float ov = oacc[nb][j] * linv[j];
      ushort hi, lo;
      splitf(ov, hi, lo);
      Oh[(size_t)row * DMODEL + col] = hi;
      Ol[(size_t)row * DMODEL + col] = lo;
    }
}

extern "C" void kernel_launch(void* const* d_in, const int* in_sizes, int n_in,
                              void* d_out, int out_size, void* d_ws, size_t ws_size,
                              hipStream_t stream) {
  (void)in_sizes; (void)n_in; (void)out_size; (void)ws_size;
  const float* X  = (const float*)d_in[0];
  const float* Wq = (const float*)d_in[1];
  const float* Wk = (const float*)d_in[2];
  const float* Wv = (const float*)d_in[3];
  const float* Wo = (const float*)d_in[4];
  const int* pos  = (const int*)d_in[5];
  float* out = (float*)d_out;

  ushort* wb = (ushort*)d_ws;
  const size_t SD = (size_t)S_LEN * DMODEL;       // 8388608 elements
  const size_t DD = (size_t)DMODEL * DMODEL;      // 4194304 elements (one weight matrix)

  ushort* Xh = wb;             // slot0: later Ol
  ushort* Xl = wb + SD;        // slot1
  ushort* Qr = wb + 2 * SD;    // slot2: roped in place
  ushort* Kr = wb + 3 * SD;    // slot3
  ushort* Vr = wb + 4 * SD;    // slot4: later Oh
  ushort* Vt = wb + 5 * SD;    // slot5
  ushort* W0h = wb + 6 * SD;           // Wq, then Wo
  ushort* W0l = wb + 6 * SD + DD;
  ushort* W1h = wb + 7 * SD;           // Wk
  ushort* W1l = wb + 7 * SD + DD;
  ushort* W2h = wb + 8 * SD;           // Wv
  ushort* W2l = wb + 8 * SD + DD;
  float* cosT = (float*)(wb + 9 * SD);
  float* sinT = cosT + (size_t)S_LEN * 64;
  ushort* OhB = Vr;  // reuse
  ushort* OlB = Xh;  // reuse

  rope_table_kernel<<<S_LEN * 64 / 256, 256, 0, stream>>>(cosT, sinT);
  split_kernel<<<SD / 1024, 256, 0, stream>>>(X, Xh, Xl);
  split_kernel<<<DD / 1024, 256, 0, stream>>>(Wq, W0h, W0l);
  split_kernel<<<DD / 1024, 256, 0, stream>>>(Wk, W1h, W1l);
  split_kernel<<<DD / 1024, 256, 0, stream>>>(Wv, W2h, W2l);

  dim3 gemmGrid(DMODEL / 128, S_LEN / 128);
  gemm3<<<gemmGrid, 256, 0, stream>>>(Xh, Xl, W0h, W0l, Qr, S_LEN, DMODEL, DMODEL, 0);
  split_kernel<<<DD / 1024, 256, 0, stream>>>(Wo, W0h, W0l);  // after Q-GEMM
  gemm3<<<gemmGrid, 256, 0, stream>>>(Xh, Xl, W1h, W1l, Kr, S_LEN, DMODEL, DMODEL, 0);
  gemm3<<<gemmGrid, 256, 0, stream>>>(Xh, Xl, W2h, W2l, Vr, S_LEN, DMODEL, DMODEL, 0);

  rope2_kernel<<<(S_LEN * 1024) / 256, 256, 0, stream>>>(Qr, Kr, pos, cosT, sinT);
  transpose_kernel<<<dim3(S_LEN / 64, DMODEL / 64), 256, 0, stream>>>(Vr, Vt);

  flash3_kernel<<<dim3(S_LEN / 128, NHEADS), 512, 0, stream>>>(Qr, Kr, Vt, OhB, OlB);

  gemm3<<<gemmGrid, 256, 0, stream>>>(OhB, OlB, W0h, W0l, out, S_LEN, DMODEL, DMODEL, 1);
}

// Round 5
// 624.445 us; speedup vs baseline: 1.2370x; 1.2370x over previous
//
#include <hip/hip_runtime.h>
#include <hip/hip_bf16.h>

#define S_LEN 4096
#define DMODEL 2048
#define NHEADS 16
#define HEADDIM 128

typedef __attribute__((ext_vector_type(8))) short bf16x8;
typedef __attribute__((ext_vector_type(4))) float f32x4;

__device__ __forceinline__ float bf2f(ushort u) {
  union { unsigned int i; float f; } x; x.i = ((unsigned int)u) << 16; return x.f;
}
__device__ __forceinline__ ushort f2bf(float f) {
  union { float f; unsigned int i; } x; x.f = f;
  unsigned int u = x.i;
  unsigned int r = u + 0x7fffu + ((u >> 16) & 1u);
  return (ushort)(r >> 16);
}
__device__ __forceinline__ void splitf(float f, ushort& h, ushort& l) {
  unsigned int u = __float_as_uint(f);
  h = (ushort)(u >> 16);
  l = f2bf(f - __uint_as_float(u & 0xffff0000u));
}
__device__ __forceinline__ unsigned int cvtpk(float a, float b) {
  unsigned int r;
  asm("v_cvt_pk_bf16_f32 %0, %1, %2" : "=v"(r) : "v"(a), "v"(b));
  return r;  // lo = bf16(a), hi = bf16(b)
}

__device__ __forceinline__ void gload16(const ushort* g, ushort* l) {
  __builtin_amdgcn_global_load_lds(
      (const __attribute__((address_space(1))) unsigned int*)g,
      (__attribute__((address_space(3))) unsigned int*)l, 16, 0, 0);
}

// ---------------- RoPE cos/sin table: [S][64] each ----------------
__global__ __launch_bounds__(256) void rope_table_kernel(float* __restrict__ cosT,
                                                         float* __restrict__ sinT) {
  int idx = blockIdx.x * 256 + threadIdx.x;  // S*64
  int t = idx >> 6, j = idx & 63;
  float expo = (float)(2 * j) / 128.0f;
  float inv = 1.0f / powf(10000.0f, expo);
  float f = (float)t * inv;
  cosT[idx] = cosf(f);
  sinT[idx] = sinf(f);
}

// ---------------- fp32 -> bf16 hi/lo split ----------------
__global__ __launch_bounds__(256) void split_kernel(const float* __restrict__ in,
                                                    ushort* __restrict__ hi,
                                                    ushort* __restrict__ lo) {
  int i = (blockIdx.x * 256 + threadIdx.x) * 4;
  float4 v = *reinterpret_cast<const float4*>(&in[i]);
  ushort4 h, l;
  splitf(v.x, h.x, l.x);
  splitf(v.y, h.y, l.y);
  splitf(v.z, h.z, l.z);
  splitf(v.w, h.w, l.w);
  *reinterpret_cast<ushort4*>(&hi[i]) = h;
  *reinterpret_cast<ushort4*>(&lo[i]) = l;
}

// ---------------- 3-term bf16 GEMM: C = (Ah+Al) * (Bh+Bl)^T (drop Al*Bl) ----------------
__global__ __launch_bounds__(256) void gemm3(const ushort* __restrict__ Ah_,
                                             const ushort* __restrict__ Al_,
                                             const ushort* __restrict__ Bh_,
                                             const ushort* __restrict__ Bl_,
                                             void* __restrict__ Cout,
                                             int M, int N, int K, int f32out) {
  __shared__ __align__(16) ushort sAh[128 * 32], sAl[128 * 32], sBh[128 * 32], sBl[128 * 32];
  const int tid = threadIdx.x;
  const int wave = tid >> 6, lane = tid & 63;
  const int lg = lane >> 4, lm = lane & 15;
  const int nwg = gridDim.x * gridDim.y;
  const int id = blockIdx.y * gridDim.x + blockIdx.x;
  const int cpx = nwg >> 3;
  const int swz = (id & 7) * cpx + (id >> 3);
  const int nbx = N >> 7;
  const int m0 = (swz / nbx) * 128, n0 = (swz % nbx) * 128;
  const int wm = (wave >> 1) * 64, wn = (wave & 1) * 64;
  f32x4 acc[4][4] = {};

  for (int k0 = 0; k0 < K; k0 += 32) {
    __syncthreads();
#pragma unroll
    for (int t = 0; t < 2; ++t) {
      int r = wave * 32 + t * 16 + (lane >> 2);
      int ca = (lane & 3) ^ ((r >> 1) & 3);
      size_t ga = (size_t)(m0 + r) * K + k0 + ca * 8;
      size_t gb = (size_t)(n0 + r) * K + k0 + ca * 8;
      int lb = (wave * 32 + t * 16) * 32;
      gload16(&Ah_[ga], &sAh[lb]);
      gload16(&Al_[ga], &sAl[lb]);
      gload16(&Bh_[gb], &sBh[lb]);
      gload16(&Bl_[gb], &sBl[lb]);
    }
    __syncthreads();
    bf16x8 ah[4], al[4], bh[4], bl[4];
#pragma unroll
    for (int t = 0; t < 4; ++t) {
      int Ra = wm + t * 16 + lm;
      int Rb = wn + t * 16 + lm;
      int ca = (lg ^ ((Ra >> 1) & 3)) * 8;
      int cb = (lg ^ ((Rb >> 1) & 3)) * 8;
      ah[t] = *reinterpret_cast<const bf16x8*>(&sAh[Ra * 32 + ca]);
      al[t] = *reinterpret_cast<const bf16x8*>(&sAl[Ra * 32 + ca]);
      bh[t] = *reinterpret_cast<const bf16x8*>(&sBh[Rb * 32 + cb]);
      bl[t] = *reinterpret_cast<const bf16x8*>(&sBl[Rb * 32 + cb]);
    }
#pragma unroll
    for (int mi = 0; mi < 4; ++mi)
#pragma unroll
      for (int ni = 0; ni < 4; ++ni) {
        acc[mi][ni] = __builtin_amdgcn_mfma_f32_16x16x32_bf16(ah[mi], bh[ni], acc[mi][ni], 0, 0, 0);
        acc[mi][ni] = __builtin_amdgcn_mfma_f32_16x16x32_bf16(ah[mi], bl[ni], acc[mi][ni], 0, 0, 0);
        acc[mi][ni] = __builtin_amdgcn_mfma_f32_16x16x32_bf16(al[mi], bh[ni], acc[mi][ni], 0, 0, 0);
      }
  }
  if (f32out) {
    float* C = (float*)Cout;
#pragma unroll
    for (int mi = 0; mi < 4; ++mi)
#pragma unroll
      for (int ni = 0; ni < 4; ++ni)
#pragma unroll
        for (int j = 0; j < 4; ++j) {
          int row = m0 + wm + mi * 16 + lg * 4 + j;
          int col = n0 + wn + ni * 16 + lm;
          C[(size_t)row * N + col] = acc[mi][ni][j];
        }
  } else {
    ushort* C = (ushort*)Cout;
#pragma unroll
    for (int mi = 0; mi < 4; ++mi)
#pragma unroll
      for (int ni = 0; ni < 4; ++ni)
#pragma unroll
        for (int j = 0; j < 4; ++j) {
          int row = m0 + wm + mi * 16 + lg * 4 + j;
          int col = n0 + wn + ni * 16 + lm;
          C[(size_t)row * N + col] = f2bf(acc[mi][ni][j]);
        }
  }
}

// ---------------- RoPE in-place on Q (scaled 1/sqrt(HD)) and K ----------------
__global__ __launch_bounds__(256) void rope2_kernel(ushort* __restrict__ Q,
                                                    ushort* __restrict__ K,
                                                    const int* __restrict__ pos,
                                                    const float* __restrict__ cosT,
                                                    const float* __restrict__ sinT) {
  int idx = blockIdx.x * 256 + threadIdx.x;  // S*1024 (pairs)
  int s = idx >> 10, dh = idx & 1023;
  int hh = dh >> 6, j = dh & 63;
  int p = pos[s];
  float cs = cosT[p * 64 + j], sn = sinT[p * 64 + j];
  size_t i1 = (size_t)s * DMODEL + hh * HEADDIM + j, i2 = i1 + 64;
  float q1 = bf2f(Q[i1]), q2 = bf2f(Q[i2]);
  float k1 = bf2f(K[i1]), k2 = bf2f(K[i2]);
  const float scl = 0.08838834764831845f;  // 1/sqrt(128)
  Q[i1] = f2bf((q1 * cs - q2 * sn) * scl);
  Q[i2] = f2bf((q2 * cs + q1 * sn) * scl);
  K[i1] = f2bf(k1 * cs - k2 * sn);
  K[i2] = f2bf(k2 * cs + k1 * sn);
}

// ---------------- V transpose: Vr [S][D] -> Vt [D][S] (bf16) ----------------
__global__ __launch_bounds__(256) void transpose_kernel(const ushort* __restrict__ Vr,
                                                        ushort* __restrict__ Vt) {
  __shared__ __align__(16) ushort tile[64 * 72];
  int tid = threadIdx.x;
  int s0 = blockIdx.x * 64, c0 = blockIdx.y * 64;
#pragma unroll
  for (int it = 0; it < 2; ++it) {
    int i = tid + it * 256;
    int r = i >> 3, c = i & 7;
    *reinterpret_cast<uint4*>(&tile[r * 72 + c * 8]) =
        *reinterpret_cast<const uint4*>(&Vr[(size_t)(s0 + r) * DMODEL + c0 + c * 8]);
  }
  __syncthreads();
#pragma unroll
  for (int it = 0; it < 2; ++it) {
    int i = tid + it * 256;
    int cr = i >> 3, sc = i & 7;
    ushort tmp[8];
#pragma unroll
    for (int j = 0; j < 8; ++j) tmp[j] = tile[(sc * 8 + j) * 72 + cr];
    *reinterpret_cast<uint4*>(&Vt[(size_t)(c0 + cr) * S_LEN + s0 + sc * 8]) =
        *reinterpret_cast<uint4*>(tmp);
  }
}

// ---------------- Flash attention v5 ----------------
// 8 waves x 32 q-rows (2 q-groups of 16), QBLK=256, KBLK=64, 1 block/CU.
// Swapped QK^T (mfma(K,Q)) + key permutation rho staged via per-lane
// global_load_lds source addresses; LDS linear + XOR-16B-chunk swizzle
// (pc = cc ^ (row&7)) applied identically on stage-source and read.
// Double-buffered LDS, one barrier per tile.
__global__ __launch_bounds__(512, 2) void flash5_kernel(const ushort* __restrict__ Q,
                                                        const ushort* __restrict__ Kb,
                                                        const ushort* __restrict__ Vt,
                                                        ushort* __restrict__ Oh,
                                                        ushort* __restrict__ Ol) {
  __shared__ __align__(16) ushort Kt[2][64 * 128];
  __shared__ __align__(16) ushort Vs[2][128 * 64];
  const int tid = threadIdx.x;
  const int wave = tid >> 6, lane = tid & 63;
  const int lg = lane >> 4, lm = lane & 15;
  const int id = blockIdx.y * gridDim.x + blockIdx.x;  // 0..255
  const int o = (id & 7) * 32 + (id >> 3);             // XCD swizzle (256 = 8*32)
  const int h = o >> 4;
  const int q0 = (o & 15) * 256;

  // Q fragments for the wave's two q-groups
  bf16x8 qh[2][4];
#pragma unroll
  for (int t2 = 0; t2 < 2; ++t2) {
    int qrow = q0 + wave * 32 + t2 * 16 + lm;
#pragma unroll
    for (int kc = 0; kc < 4; ++kc)
      qh[t2][kc] = *reinterpret_cast<const bf16x8*>(
          &Q[(size_t)qrow * DMODEL + h * HEADDIM + kc * 32 + lg * 8]);
  }

  // ---- staging geometry (per-thread constants) ----
  // chunk indices this thread covers (2 gloads for K, 2 for V)
  const int ci0 = wave * 128 + lane;
  const int ci1 = ci0 + 64;
  // K: LDS row s (permuted-key slot), physical chunk ci&15, logical cc = pc^(s&7)
  auto rho = [](int s) {
    return 32 * ((s >> 4) & 1) + 8 * ((s >> 2) & 3) + 4 * (s >> 5) + (s & 3);
  };
  const int ks0 = ci0 >> 4, ks1 = ci1 >> 4;
  const int kcc0 = (ci0 & 15) ^ (ks0 & 7), kcc1 = (ci1 & 15) ^ (ks1 & 7);
  const ushort* pK0 = Kb + (size_t)rho(ks0) * DMODEL + h * HEADDIM + kcc0 * 8;
  const ushort* pK1 = Kb + (size_t)rho(ks1) * DMODEL + h * HEADDIM + kcc1 * 8;
  // V: LDS row d, physical chunk ci&7, logical cc = pc^(d&7)
  const int vd0 = ci0 >> 3, vd1 = ci1 >> 3;
  const int vcc0 = (ci0 & 7) ^ (vd0 & 7), vcc1 = (ci1 & 7) ^ (vd1 & 7);
  const ushort* pV0 = Vt + (size_t)(h * HEADDIM + vd0) * S_LEN + vcc0 * 8;
  const ushort* pV1 = Vt + (size_t)(h * HEADDIM + vd1) * S_LEN + vcc1 * 8;
  const int lbase = wave * 1024;  // ushort index of this wave's chunk region

  f32x4 oacc[2][8] = {};
  float mrun[2], osum[2];
#pragma unroll
  for (int t2 = 0; t2 < 2; ++t2) { mrun[t2] = -3.0e38f; osum[t2] = 0.0f; }

  // prologue: stage tile 0 into buf 0
  {
    gload16(pK0, &Kt[0][lbase]);
    gload16(pK1, &Kt[0][lbase + 512]);
    gload16(pV0, &Vs[0][lbase]);
    gload16(pV1, &Vs[0][lbase + 512]);
  }
  __syncthreads();

  for (int t = 0; t < S_LEN / 64; ++t) {
    const int cur = t & 1;
    if (t < S_LEN / 64 - 1) {
      const size_t koff = (size_t)(t + 1) * 64;
      gload16(pK0 + koff * DMODEL, &Kt[cur ^ 1][lbase]);
      gload16(pK1 + koff * DMODEL, &Kt[cur ^ 1][lbase + 512]);
      gload16(pV0 + koff, &Vs[cur ^ 1][lbase]);
      gload16(pV1 + koff, &Vs[cur ^ 1][lbase + 512]);
    }
    const ushort* Kc = &Kt[cur][0];
    const ushort* Vc = &Vs[cur][0];

    // QK^T swapped: st[t2][nf][j] = S[q][key rho(nf*16+lg*4+j)] for q-group t2
    f32x4 st[2][4] = {};
#pragma unroll
    for (int nf = 0; nf < 4; ++nf)
#pragma unroll
      for (int kc = 0; kc < 4; ++kc) {
        int pc = (kc * 4 + lg) ^ (lm & 7);
        bf16x8 kfrag = *reinterpret_cast<const bf16x8*>(&Kc[(nf * 16 + lm) * 128 + pc * 8]);
        st[0][nf] = __builtin_amdgcn_mfma_f32_16x16x32_bf16(kfrag, qh[0][kc], st[0][nf], 0, 0, 0);
        st[1][nf] = __builtin_amdgcn_mfma_f32_16x16x32_bf16(kfrag, qh[1][kc], st[1][nf], 0, 0, 0);
      }

    // in-lane row max (q = lm) + replica reduce
    float m16[2];
#pragma unroll
    for (int t2 = 0; t2 < 2; ++t2) {
      float m = st[t2][0][0];
#pragma unroll
      for (int nf = 0; nf < 4; ++nf)
#pragma unroll
        for (int j = 0; j < 4; ++j) m = fmaxf(m, st[t2][nf][j]);
      m = fmaxf(m, __shfl_xor(m, 16));
      m = fmaxf(m, __shfl_xor(m, 32));
      m16[t2] = m;
    }

    // defer-max rescale
    bool grow = (m16[0] > mrun[0] + 8.0f) || (m16[1] > mrun[1] + 8.0f);
    if (__any(grow)) {
#pragma unroll
      for (int t2 = 0; t2 < 2; ++t2) {
        float mn = fmaxf(mrun[t2], m16[t2]);
        float scl = __expf(mrun[t2] - mn);
        mrun[t2] = mn;
        osum[t2] *= scl;
        float sj[4];
#pragma unroll
        for (int j = 0; j < 4; ++j) sj[j] = __shfl(scl, lg * 4 + j);
#pragma unroll
        for (int nb = 0; nb < 8; ++nb)
#pragma unroll
          for (int j = 0; j < 4; ++j) oacc[t2][nb][j] *= sj[j];
      }
    }

    // P = exp(S - m) in place; in-lane sum
#pragma unroll
    for (int t2 = 0; t2 < 2; ++t2) {
      float rs = 0.0f;
#pragma unroll
      for (int nf = 0; nf < 4; ++nf)
#pragma unroll
        for (int j = 0; j < 4; ++j) {
          float pv = __expf(st[t2][nf][j] - mrun[t2]);
          st[t2][nf][j] = pv;
          rs += pv;
        }
      rs += __shfl_xor(rs, 16);
      rs += __shfl_xor(rs, 32);
      osum[t2] += rs;
    }

    // pack to PV A-frags: pa[t2][kk] = {st[t2][kk][0..3], st[t2][2+kk][0..3]} as bf16
    bf16x8 pa[2][2];
#pragma unroll
    for (int t2 = 0; t2 < 2; ++t2)
#pragma unroll
      for (int kk = 0; kk < 2; ++kk) {
        union { unsigned int u[4]; bf16x8 v; } w_;
        w_.u[0] = cvtpk(st[t2][kk][0], st[t2][kk][1]);
        w_.u[1] = cvtpk(st[t2][kk][2], st[t2][kk][3]);
        w_.u[2] = cvtpk(st[t2][2 + kk][0], st[t2][2 + kk][1]);
        w_.u[3] = cvtpk(st[t2][2 + kk][2], st[t2][2 + kk][3]);
        pa[t2][kk] = w_.v;
      }

    // PV: vfrag read once, used by both q-groups
#pragma unroll
    for (int nb = 0; nb < 8; ++nb)
#pragma unroll
      for (int kk = 0; kk < 2; ++kk) {
        int pc = (kk * 4 + lg) ^ (lm & 7);
        bf16x8 vfrag = *reinterpret_cast<const bf16x8*>(&Vc[(nb * 16 + lm) * 64 + pc * 8]);
        oacc[0][nb] = __builtin_amdgcn_mfma_f32_16x16x32_bf16(pa[0][kk], vfrag, oacc[0][nb], 0, 0, 0);
        oacc[1][nb] = __builtin_amdgcn_mfma_f32_16x16x32_bf16(pa[1][kk], vfrag, oacc[1][nb], 0, 0, 0);
      }

    __syncthreads();  // drains next-tile gloads (overlapped with compute) + joins waves
  }

  // epilogue
#pragma unroll
  for (int t2 = 0; t2 < 2; ++t2) {
    float inv = 1.0f / osum[t2];
    float linv[4];
#pragma unroll
    for (int j = 0; j < 4; ++j) linv[j] = __shfl(inv, lg * 4 + j);
#pragma unroll
    for (int nb = 0; nb < 8; ++nb)
#pragma unroll
      for (int j = 0; j < 4; ++j) {
        int row = q0 + wave * 32 + t2 * 16 + lg * 4 + j;
        int col = h * HEADDIM + nb * 16 + lm;
        float ov = oacc[t2][nb][j] * linv[j];
        ushort hi, lo;
        splitf(ov, hi, lo);
        Oh[(size_t)row * DMODEL + col] = hi;
        Ol[(size_t)row * DMODEL + col] = lo;
      }
  }
}

extern "C" void kernel_launch(void* const* d_in, const int* in_sizes, int n_in,
                              void* d_out, int out_size, void* d_ws, size_t ws_size,
                              hipStream_t stream) {
  (void)in_sizes; (void)n_in; (void)out_size; (void)ws_size;
  const float* X  = (const float*)d_in[0];
  const float* Wq = (const float*)d_in[1];
  const float* Wk = (const float*)d_in[2];
  const float* Wv = (const float*)d_in[3];
  const float* Wo = (const float*)d_in[4];
  const int* pos  = (const int*)d_in[5];
  float* out = (float*)d_out;

  ushort* wb = (ushort*)d_ws;
  const size_t SD = (size_t)S_LEN * DMODEL;       // 8388608 elements
  const size_t DD = (size_t)DMODEL * DMODEL;      // 4194304 elements (one weight matrix)

  ushort* Xh = wb;             // slot0: later Ol
  ushort* Xl = wb + SD;        // slot1
  ushort* Qr = wb + 2 * SD;    // slot2: roped in place
  ushort* Kr = wb + 3 * SD;    // slot3
  ushort* Vr = wb + 4 * SD;    // slot4: later Oh
  ushort* Vt = wb + 5 * SD;    // slot5
  ushort* W0h = wb + 6 * SD;           // Wq, then Wo
  ushort* W0l = wb + 6 * SD + DD;
  ushort* W1h = wb + 7 * SD;           // Wk
  ushort* W1l = wb + 7 * SD + DD;
  ushort* W2h = wb + 8 * SD;           // Wv
  ushort* W2l = wb + 8 * SD + DD;
  float* cosT = (float*)(wb + 9 * SD);
  float* sinT = cosT + (size_t)S_LEN * 64;
  ushort* OhB = Vr;  // reuse
  ushort* OlB = Xh;  // reuse

  rope_table_kernel<<<S_LEN * 64 / 256, 256, 0, stream>>>(cosT, sinT);
  split_kernel<<<SD / 1024, 256, 0, stream>>>(X, Xh, Xl);
  split_kernel<<<DD / 1024, 256, 0, stream>>>(Wq, W0h, W0l);
  split_kernel<<<DD / 1024, 256, 0, stream>>>(Wk, W1h, W1l);
  split_kernel<<<DD / 1024, 256, 0, stream>>>(Wv, W2h, W2l);

  dim3 gemmGrid(DMODEL / 128, S_LEN / 128);
  gemm3<<<gemmGrid, 256, 0, stream>>>(Xh, Xl, W0h, W0l, Qr, S_LEN, DMODEL, DMODEL, 0);
  split_kernel<<<DD / 1024, 256, 0, stream>>>(Wo, W0h, W0l);  // after Q-GEMM
  gemm3<<<gemmGrid, 256, 0, stream>>>(Xh, Xl, W1h, W1l, Kr, S_LEN, DMODEL, DMODEL, 0);
  gemm3<<<gemmGrid, 256, 0, stream>>>(Xh, Xl, W2h, W2l, Vr, S_LEN, DMODEL, DMODEL, 0);

  rope2_kernel<<<(S_LEN * 1024) / 256, 256, 0, stream>>>(Qr, Kr, pos, cosT, sinT);
  transpose_kernel<<<dim3(S_LEN / 64, DMODEL / 64), 256, 0, stream>>>(Vr, Vt);

  flash5_kernel<<<dim3(16, 16), 512, 0, stream>>>(Qr, Kr, Vt, OhB, OlB);

  gemm3<<<gemmGrid, 256, 0, stream>>>(OhB, OlB, W0h, W0l, out, S_LEN, DMODEL, DMODEL, 1);
}

// Round 6
// 520.742 us; speedup vs baseline: 1.4833x; 1.1991x over previous
//
#include <hip/hip_runtime.h>
#include <hip/hip_bf16.h>

#define S_LEN 4096
#define DMODEL 2048
#define NHEADS 16
#define HEADDIM 128

typedef __attribute__((ext_vector_type(8))) short bf16x8;
typedef __attribute__((ext_vector_type(4))) float f32x4;

__device__ __forceinline__ float bf2f(ushort u) {
  union { unsigned int i; float f; } x; x.i = ((unsigned int)u) << 16; return x.f;
}
__device__ __forceinline__ ushort f2bf(float f) {
  union { float f; unsigned int i; } x; x.f = f;
  unsigned int u = x.i;
  unsigned int r = u + 0x7fffu + ((u >> 16) & 1u);
  return (ushort)(r >> 16);
}
__device__ __forceinline__ void splitf(float f, ushort& h, ushort& l) {
  unsigned int u = __float_as_uint(f);
  h = (ushort)(u >> 16);
  l = f2bf(f - __uint_as_float(u & 0xffff0000u));
}
__device__ __forceinline__ unsigned int cvtpk(float a, float b) {
  unsigned int r;
  asm("v_cvt_pk_bf16_f32 %0, %1, %2" : "=v"(r) : "v"(a), "v"(b));
  return r;
}

__device__ __forceinline__ void gload16(const ushort* g, ushort* l) {
  __builtin_amdgcn_global_load_lds(
      (const __attribute__((address_space(1))) unsigned int*)g,
      (__attribute__((address_space(3))) unsigned int*)l, 16, 0, 0);
}

// ---------------- RoPE cos/sin table ----------------
__global__ __launch_bounds__(256) void rope_table_kernel(float* __restrict__ cosT,
                                                         float* __restrict__ sinT) {
  int idx = blockIdx.x * 256 + threadIdx.x;
  int t = idx >> 6, j = idx & 63;
  float expo = (float)(2 * j) / 128.0f;
  float inv = 1.0f / powf(10000.0f, expo);
  float f = (float)t * inv;
  cosT[idx] = cosf(f);
  sinT[idx] = sinf(f);
}

// ---------------- fp32 -> bf16 hi/lo split ----------------
__global__ __launch_bounds__(256) void split_kernel(const float* __restrict__ in,
                                                    ushort* __restrict__ hi,
                                                    ushort* __restrict__ lo) {
  int i = (blockIdx.x * 256 + threadIdx.x) * 4;
  float4 v = *reinterpret_cast<const float4*>(&in[i]);
  ushort4 h, l;
  splitf(v.x, h.x, l.x);
  splitf(v.y, h.y, l.y);
  splitf(v.z, h.z, l.z);
  splitf(v.w, h.w, l.w);
  *reinterpret_cast<ushort4*>(&hi[i]) = h;
  *reinterpret_cast<ushort4*>(&lo[i]) = l;
}

// ---------------- fp32 -> bf16 (RNE) convert, hi only ----------------
__global__ __launch_bounds__(256) void convert_kernel(const float* __restrict__ in,
                                                      ushort* __restrict__ hi) {
  int i = (blockIdx.x * 256 + threadIdx.x) * 4;
  float4 v = *reinterpret_cast<const float4*>(&in[i]);
  ushort4 h;
  h.x = f2bf(v.x); h.y = f2bf(v.y); h.z = f2bf(v.z); h.w = f2bf(v.w);
  *reinterpret_cast<ushort4*>(&hi[i]) = h;
}

// ---------------- 2-term bf16 GEMM: C = (Ah+Al) * Bh^T ----------------
__global__ __launch_bounds__(256) void gemm2(const ushort* __restrict__ Ah_,
                                             const ushort* __restrict__ Al_,
                                             const ushort* __restrict__ Bh_,
                                             ushort* __restrict__ Cout,
                                             int M, int N, int K) {
  __shared__ __align__(16) ushort sAh[128 * 32], sAl[128 * 32], sBh[128 * 32];
  const int tid = threadIdx.x;
  const int wave = tid >> 6, lane = tid & 63;
  const int lg = lane >> 4, lm = lane & 15;
  const int nwg = gridDim.x * gridDim.y;
  const int id = blockIdx.y * gridDim.x + blockIdx.x;
  const int cpx = nwg >> 3;
  const int swz = (id & 7) * cpx + (id >> 3);
  const int nbx = N >> 7;
  const int m0 = (swz / nbx) * 128, n0 = (swz % nbx) * 128;
  const int wm = (wave >> 1) * 64, wn = (wave & 1) * 64;
  f32x4 acc[4][4] = {};

  for (int k0 = 0; k0 < K; k0 += 32) {
    __syncthreads();
#pragma unroll
    for (int t = 0; t < 2; ++t) {
      int r = wave * 32 + t * 16 + (lane >> 2);
      int ca = (lane & 3) ^ ((r >> 1) & 3);
      size_t ga = (size_t)(m0 + r) * K + k0 + ca * 8;
      size_t gb = (size_t)(n0 + r) * K + k0 + ca * 8;
      int lb = (wave * 32 + t * 16) * 32;
      gload16(&Ah_[ga], &sAh[lb]);
      gload16(&Al_[ga], &sAl[lb]);
      gload16(&Bh_[gb], &sBh[lb]);
    }
    __syncthreads();
    bf16x8 ah[4], al[4], bh[4];
#pragma unroll
    for (int t = 0; t < 4; ++t) {
      int Ra = wm + t * 16 + lm;
      int Rb = wn + t * 16 + lm;
      int ca = (lg ^ ((Ra >> 1) & 3)) * 8;
      int cb = (lg ^ ((Rb >> 1) & 3)) * 8;
      ah[t] = *reinterpret_cast<const bf16x8*>(&sAh[Ra * 32 + ca]);
      al[t] = *reinterpret_cast<const bf16x8*>(&sAl[Ra * 32 + ca]);
      bh[t] = *reinterpret_cast<const bf16x8*>(&sBh[Rb * 32 + cb]);
    }
#pragma unroll
    for (int mi = 0; mi < 4; ++mi)
#pragma unroll
      for (int ni = 0; ni < 4; ++ni) {
        acc[mi][ni] = __builtin_amdgcn_mfma_f32_16x16x32_bf16(ah[mi], bh[ni], acc[mi][ni], 0, 0, 0);
        acc[mi][ni] = __builtin_amdgcn_mfma_f32_16x16x32_bf16(al[mi], bh[ni], acc[mi][ni], 0, 0, 0);
      }
  }
#pragma unroll
  for (int mi = 0; mi < 4; ++mi)
#pragma unroll
    for (int ni = 0; ni < 4; ++ni)
#pragma unroll
      for (int j = 0; j < 4; ++j) {
        int row = m0 + wm + mi * 16 + lg * 4 + j;
        int col = n0 + wn + ni * 16 + lm;
        Cout[(size_t)row * N + col] = f2bf(acc[mi][ni][j]);
      }
}

// ---------------- 3-term bf16 GEMM (for Wo, f32 out) ----------------
__global__ __launch_bounds__(256) void gemm3(const ushort* __restrict__ Ah_,
                                             const ushort* __restrict__ Al_,
                                             const ushort* __restrict__ Bh_,
                                             const ushort* __restrict__ Bl_,
                                             float* __restrict__ Cout,
                                             int M, int N, int K) {
  __shared__ __align__(16) ushort sAh[128 * 32], sAl[128 * 32], sBh[128 * 32], sBl[128 * 32];
  const int tid = threadIdx.x;
  const int wave = tid >> 6, lane = tid & 63;
  const int lg = lane >> 4, lm = lane & 15;
  const int nwg = gridDim.x * gridDim.y;
  const int id = blockIdx.y * gridDim.x + blockIdx.x;
  const int cpx = nwg >> 3;
  const int swz = (id & 7) * cpx + (id >> 3);
  const int nbx = N >> 7;
  const int m0 = (swz / nbx) * 128, n0 = (swz % nbx) * 128;
  const int wm = (wave >> 1) * 64, wn = (wave & 1) * 64;
  f32x4 acc[4][4] = {};

  for (int k0 = 0; k0 < K; k0 += 32) {
    __syncthreads();
#pragma unroll
    for (int t = 0; t < 2; ++t) {
      int r = wave * 32 + t * 16 + (lane >> 2);
      int ca = (lane & 3) ^ ((r >> 1) & 3);
      size_t ga = (size_t)(m0 + r) * K + k0 + ca * 8;
      size_t gb = (size_t)(n0 + r) * K + k0 + ca * 8;
      int lb = (wave * 32 + t * 16) * 32;
      gload16(&Ah_[ga], &sAh[lb]);
      gload16(&Al_[ga], &sAl[lb]);
      gload16(&Bh_[gb], &sBh[lb]);
      gload16(&Bl_[gb], &sBl[lb]);
    }
    __syncthreads();
    bf16x8 ah[4], al[4], bh[4], bl[4];
#pragma unroll
    for (int t = 0; t < 4; ++t) {
      int Ra = wm + t * 16 + lm;
      int Rb = wn + t * 16 + lm;
      int ca = (lg ^ ((Ra >> 1) & 3)) * 8;
      int cb = (lg ^ ((Rb >> 1) & 3)) * 8;
      ah[t] = *reinterpret_cast<const bf16x8*>(&sAh[Ra * 32 + ca]);
      al[t] = *reinterpret_cast<const bf16x8*>(&sAl[Ra * 32 + ca]);
      bh[t] = *reinterpret_cast<const bf16x8*>(&sBh[Rb * 32 + cb]);
      bl[t] = *reinterpret_cast<const bf16x8*>(&sBl[Rb * 32 + cb]);
    }
#pragma unroll
    for (int mi = 0; mi < 4; ++mi)
#pragma unroll
      for (int ni = 0; ni < 4; ++ni) {
        acc[mi][ni] = __builtin_amdgcn_mfma_f32_16x16x32_bf16(ah[mi], bh[ni], acc[mi][ni], 0, 0, 0);
        acc[mi][ni] = __builtin_amdgcn_mfma_f32_16x16x32_bf16(ah[mi], bl[ni], acc[mi][ni], 0, 0, 0);
        acc[mi][ni] = __builtin_amdgcn_mfma_f32_16x16x32_bf16(al[mi], bh[ni], acc[mi][ni], 0, 0, 0);
      }
  }
#pragma unroll
  for (int mi = 0; mi < 4; ++mi)
#pragma unroll
    for (int ni = 0; ni < 4; ++ni)
#pragma unroll
      for (int j = 0; j < 4; ++j) {
        int row = m0 + wm + mi * 16 + lg * 4 + j;
        int col = n0 + wn + ni * 16 + lm;
        Cout[(size_t)row * N + col] = acc[mi][ni][j];
      }
}

// ---------------- RoPE in-place on Q (scaled 1/sqrt(HD)) and K ----------------
__global__ __launch_bounds__(256) void rope2_kernel(ushort* __restrict__ Q,
                                                    ushort* __restrict__ K,
                                                    const int* __restrict__ pos,
                                                    const float* __restrict__ cosT,
                                                    const float* __restrict__ sinT) {
  int idx = blockIdx.x * 256 + threadIdx.x;
  int s = idx >> 10, dh = idx & 1023;
  int hh = dh >> 6, j = dh & 63;
  int p = pos[s];
  float cs = cosT[p * 64 + j], sn = sinT[p * 64 + j];
  size_t i1 = (size_t)s * DMODEL + hh * HEADDIM + j, i2 = i1 + 64;
  float q1 = bf2f(Q[i1]), q2 = bf2f(Q[i2]);
  float k1 = bf2f(K[i1]), k2 = bf2f(K[i2]);
  const float scl = 0.08838834764831845f;
  Q[i1] = f2bf((q1 * cs - q2 * sn) * scl);
  Q[i2] = f2bf((q2 * cs + q1 * sn) * scl);
  K[i1] = f2bf(k1 * cs - k2 * sn);
  K[i2] = f2bf(k2 * cs + k1 * sn);
}

// ---------------- V transpose ----------------
__global__ __launch_bounds__(256) void transpose_kernel(const ushort* __restrict__ Vr,
                                                        ushort* __restrict__ Vt) {
  __shared__ __align__(16) ushort tile[64 * 72];
  int tid = threadIdx.x;
  int s0 = blockIdx.x * 64, c0 = blockIdx.y * 64;
#pragma unroll
  for (int it = 0; it < 2; ++it) {
    int i = tid + it * 256;
    int r = i >> 3, c = i & 7;
    *reinterpret_cast<uint4*>(&tile[r * 72 + c * 8]) =
        *reinterpret_cast<const uint4*>(&Vr[(size_t)(s0 + r) * DMODEL + c0 + c * 8]);
  }
  __syncthreads();
#pragma unroll
  for (int it = 0; it < 2; ++it) {
    int i = tid + it * 256;
    int cr = i >> 3, sc = i & 7;
    ushort tmp[8];
#pragma unroll
    for (int j = 0; j < 8; ++j) tmp[j] = tile[(sc * 8 + j) * 72 + cr];
    *reinterpret_cast<uint4*>(&Vt[(size_t)(c0 + cr) * S_LEN + s0 + sc * 8]) =
        *reinterpret_cast<uint4*>(tmp);
  }
}

// ---------------- Flash attention v6: 4 waves x 32 q-rows, 2 blocks/CU ----------------
// Same math/layout as v5 (swapped QK^T, key permutation rho via per-lane gload_lds
// source addresses, linear LDS + XOR-chunk swizzle, double-buffered), but QBLK=128
// with 4 waves so two blocks co-reside per CU and overlap each other's stalls.
__global__ __launch_bounds__(256, 2) void flash6_kernel(const ushort* __restrict__ Q,
                                                        const ushort* __restrict__ Kb,
                                                        const ushort* __restrict__ Vt,
                                                        ushort* __restrict__ Oh,
                                                        ushort* __restrict__ Ol) {
  __shared__ __align__(16) ushort Kt[2][64 * 128];
  __shared__ __align__(16) ushort Vs[2][128 * 64];
  const int tid = threadIdx.x;             // 0..255
  const int wave = tid >> 6, lane = tid & 63;
  const int lg = lane >> 4, lm = lane & 15;
  const int id = blockIdx.y * gridDim.x + blockIdx.x;  // 0..511
  const int o = (id & 7) * 64 + (id >> 3);             // XCD swizzle (512 = 8*64)
  const int h = o >> 5;
  const int q0 = (o & 31) * 128;

  bf16x8 qh[2][4];
#pragma unroll
  for (int t2 = 0; t2 < 2; ++t2) {
    int qrow = q0 + wave * 32 + t2 * 16 + lm;
#pragma unroll
    for (int kc = 0; kc < 4; ++kc)
      qh[t2][kc] = *reinterpret_cast<const bf16x8*>(
          &Q[(size_t)qrow * DMODEL + h * HEADDIM + kc * 32 + lg * 8]);
  }

  // staging: 1024 K-chunks + 1024 V-chunks, 256 threads -> 4 each
  auto rho = [](int s) {
    return 32 * ((s >> 4) & 1) + 8 * ((s >> 2) & 3) + 4 * (s >> 5) + (s & 3);
  };
  const ushort* pK[4];
  const ushort* pV[4];
  int lbs[4];
#pragma unroll
  for (int k = 0; k < 4; ++k) {
    int ci = k * 256 + wave * 64 + lane;
    int ks = ci >> 4;
    int kcc = (ci & 15) ^ (ks & 7);
    pK[k] = Kb + (size_t)rho(ks) * DMODEL + h * HEADDIM + kcc * 8;
    int vd = ci >> 3;
    int vcc = (ci & 7) ^ (vd & 7);
    pV[k] = Vt + (size_t)(h * HEADDIM + vd) * S_LEN + vcc * 8;
    lbs[k] = (k * 256 + wave * 64) * 8;  // wave-uniform ushort base
  }

  f32x4 oacc[2][8] = {};
  float mrun[2], osum[2];
#pragma unroll
  for (int t2 = 0; t2 < 2; ++t2) { mrun[t2] = -3.0e38f; osum[t2] = 0.0f; }

  // prologue: stage tile 0 into buf 0
#pragma unroll
  for (int k = 0; k < 4; ++k) {
    gload16(pK[k], &Kt[0][lbs[k]]);
    gload16(pV[k], &Vs[0][lbs[k]]);
  }
  __syncthreads();

  for (int t = 0; t < S_LEN / 64; ++t) {
    const int cur = t & 1;
    if (t < S_LEN / 64 - 1) {
      const size_t koff = (size_t)(t + 1) * 64;
#pragma unroll
      for (int k = 0; k < 4; ++k) {
        gload16(pK[k] + koff * DMODEL, &Kt[cur ^ 1][lbs[k]]);
        gload16(pV[k] + koff, &Vs[cur ^ 1][lbs[k]]);
      }
    }
    const ushort* Kc = &Kt[cur][0];
    const ushort* Vc = &Vs[cur][0];

    // QK^T swapped
    f32x4 st[2][4] = {};
    __builtin_amdgcn_s_setprio(1);
#pragma unroll
    for (int nf = 0; nf < 4; ++nf)
#pragma unroll
      for (int kc = 0; kc < 4; ++kc) {
        int pc = (kc * 4 + lg) ^ (lm & 7);
        bf16x8 kfrag = *reinterpret_cast<const bf16x8*>(&Kc[(nf * 16 + lm) * 128 + pc * 8]);
        st[0][nf] = __builtin_amdgcn_mfma_f32_16x16x32_bf16(kfrag, qh[0][kc], st[0][nf], 0, 0, 0);
        st[1][nf] = __builtin_amdgcn_mfma_f32_16x16x32_bf16(kfrag, qh[1][kc], st[1][nf], 0, 0, 0);
      }
    __builtin_amdgcn_s_setprio(0);

    // row max + replica reduce
    float m16[2];
#pragma unroll
    for (int t2 = 0; t2 < 2; ++t2) {
      float m = st[t2][0][0];
#pragma unroll
      for (int nf = 0; nf < 4; ++nf)
#pragma unroll
        for (int j = 0; j < 4; ++j) m = fmaxf(m, st[t2][nf][j]);
      m = fmaxf(m, __shfl_xor(m, 16));
      m = fmaxf(m, __shfl_xor(m, 32));
      m16[t2] = m;
    }

    // defer-max rescale
    bool grow = (m16[0] > mrun[0] + 8.0f) || (m16[1] > mrun[1] + 8.0f);
    if (__any(grow)) {
#pragma unroll
      for (int t2 = 0; t2 < 2; ++t2) {
        float mn = fmaxf(mrun[t2], m16[t2]);
        float scl = __expf(mrun[t2] - mn);
        mrun[t2] = mn;
        osum[t2] *= scl;
        float sj[4];
#pragma unroll
        for (int j = 0; j < 4; ++j) sj[j] = __shfl(scl, lg * 4 + j);
#pragma unroll
        for (int nb = 0; nb < 8; ++nb)
#pragma unroll
          for (int j = 0; j < 4; ++j) oacc[t2][nb][j] *= sj[j];
      }
    }

    // P = exp(S - m); in-lane sum
#pragma unroll
    for (int t2 = 0; t2 < 2; ++t2) {
      float rs = 0.0f;
#pragma unroll
      for (int nf = 0; nf < 4; ++nf)
#pragma unroll
        for (int j = 0; j < 4; ++j) {
          float pv = __expf(st[t2][nf][j] - mrun[t2]);
          st[t2][nf][j] = pv;
          rs += pv;
        }
      rs += __shfl_xor(rs, 16);
      rs += __shfl_xor(rs, 32);
      osum[t2] += rs;
    }

    // pack PV A-frags
    bf16x8 pa[2][2];
#pragma unroll
    for (int t2 = 0; t2 < 2; ++t2)
#pragma unroll
      for (int kk = 0; kk < 2; ++kk) {
        union { unsigned int u[4]; bf16x8 v; } w_;
        w_.u[0] = cvtpk(st[t2][kk][0], st[t2][kk][1]);
        w_.u[1] = cvtpk(st[t2][kk][2], st[t2][kk][3]);
        w_.u[2] = cvtpk(st[t2][2 + kk][0], st[t2][2 + kk][1]);
        w_.u[3] = cvtpk(st[t2][2 + kk][2], st[t2][2 + kk][3]);
        pa[t2][kk] = w_.v;
      }

    // PV
    __builtin_amdgcn_s_setprio(1);
#pragma unroll
    for (int nb = 0; nb < 8; ++nb)
#pragma unroll
      for (int kk = 0; kk < 2; ++kk) {
        int pc = (kk * 4 + lg) ^ (lm & 7);
        bf16x8 vfrag = *reinterpret_cast<const bf16x8*>(&Vc[(nb * 16 + lm) * 64 + pc * 8]);
        oacc[0][nb] = __builtin_amdgcn_mfma_f32_16x16x32_bf16(pa[0][kk], vfrag, oacc[0][nb], 0, 0, 0);
        oacc[1][nb] = __builtin_amdgcn_mfma_f32_16x16x32_bf16(pa[1][kk], vfrag, oacc[1][nb], 0, 0, 0);
      }
    __builtin_amdgcn_s_setprio(0);

    __syncthreads();
  }

  // epilogue
#pragma unroll
  for (int t2 = 0; t2 < 2; ++t2) {
    float inv = 1.0f / osum[t2];
    float linv[4];
#pragma unroll
    for (int j = 0; j < 4; ++j) linv[j] = __shfl(inv, lg * 4 + j);
#pragma unroll
    for (int nb = 0; nb < 8; ++nb)
#pragma unroll
      for (int j = 0; j < 4; ++j) {
        int row = q0 + wave * 32 + t2 * 16 + lg * 4 + j;
        int col = h * HEADDIM + nb * 16 + lm;
        float ov = oacc[t2][nb][j] * linv[j];
        ushort hi, lo;
        splitf(ov, hi, lo);
        Oh[(size_t)row * DMODEL + col] = hi;
        Ol[(size_t)row * DMODEL + col] = lo;
      }
  }
}

extern "C" void kernel_launch(void* const* d_in, const int* in_sizes, int n_in,
                              void* d_out, int out_size, void* d_ws, size_t ws_size,
                              hipStream_t stream) {
  (void)in_sizes; (void)n_in; (void)out_size; (void)ws_size;
  const float* X  = (const float*)d_in[0];
  const float* Wq = (const float*)d_in[1];
  const float* Wk = (const float*)d_in[2];
  const float* Wv = (const float*)d_in[3];
  const float* Wo = (const float*)d_in[4];
  const int* pos  = (const int*)d_in[5];
  float* out = (float*)d_out;

  ushort* wb = (ushort*)d_ws;
  const size_t SD = (size_t)S_LEN * DMODEL;       // 8388608 elements
  const size_t DD = (size_t)DMODEL * DMODEL;      // 4194304 elements

  ushort* Xh = wb;             // slot0: later Ol
  ushort* Xl = wb + SD;        // slot1
  ushort* Qr = wb + 2 * SD;    // slot2
  ushort* Kr = wb + 3 * SD;    // slot3
  ushort* Vr = wb + 4 * SD;    // slot4: later Oh
  ushort* Vt = wb + 5 * SD;    // slot5
  ushort* W0h = wb + 6 * SD;           // Wq hi, then Wo hi/lo
  ushort* W0l = wb + 6 * SD + DD;
  ushort* W1h = wb + 7 * SD;           // Wk hi
  ushort* W2h = wb + 8 * SD;           // Wv hi
  float* cosT = (float*)(wb + 9 * SD);
  float* sinT = cosT + (size_t)S_LEN * 64;
  ushort* OhB = Vr;  // reuse
  ushort* OlB = Xh;  // reuse

  rope_table_kernel<<<S_LEN * 64 / 256, 256, 0, stream>>>(cosT, sinT);
  split_kernel<<<SD / 1024, 256, 0, stream>>>(X, Xh, Xl);
  convert_kernel<<<DD / 1024, 256, 0, stream>>>(Wq, W0h);
  convert_kernel<<<DD / 1024, 256, 0, stream>>>(Wk, W1h);
  convert_kernel<<<DD / 1024, 256, 0, stream>>>(Wv, W2h);

  dim3 gemmGrid(DMODEL / 128, S_LEN / 128);
  gemm2<<<gemmGrid, 256, 0, stream>>>(Xh, Xl, W0h, Qr, S_LEN, DMODEL, DMODEL);
  split_kernel<<<DD / 1024, 256, 0, stream>>>(Wo, W0h, W0l);  // after Q-GEMM
  gemm2<<<gemmGrid, 256, 0, stream>>>(Xh, Xl, W1h, Kr, S_LEN, DMODEL, DMODEL);
  gemm2<<<gemmGrid, 256, 0, stream>>>(Xh, Xl, W2h, Vr, S_LEN, DMODEL, DMODEL);

  rope2_kernel<<<(S_LEN * 1024) / 256, 256, 0, stream>>>(Qr, Kr, pos, cosT, sinT);
  transpose_kernel<<<dim3(S_LEN / 64, DMODEL / 64), 256, 0, stream>>>(Vr, Vt);

  flash6_kernel<<<dim3(32, 16), 256, 0, stream>>>(Qr, Kr, Vt, OhB, OlB);

  gemm3<<<gemmGrid, 256, 0, stream>>>(OhB, OlB, W0h, W0l, out, S_LEN, DMODEL, DMODEL);
}

// Round 7
// 449.302 us; speedup vs baseline: 1.7192x; 1.1590x over previous
//
#include <hip/hip_runtime.h>
#include <hip/hip_bf16.h>

#define S_LEN 4096
#define DMODEL 2048
#define NHEADS 16
#define HEADDIM 128

typedef __attribute__((ext_vector_type(8))) short bf16x8;
typedef __attribute__((ext_vector_type(4))) float f32x4;

__device__ __forceinline__ float bf2f(ushort u) {
  union { unsigned int i; float f; } x; x.i = ((unsigned int)u) << 16; return x.f;
}
__device__ __forceinline__ ushort f2bf(float f) {
  union { float f; unsigned int i; } x; x.f = f;
  unsigned int u = x.i;
  unsigned int r = u + 0x7fffu + ((u >> 16) & 1u);
  return (ushort)(r >> 16);
}
__device__ __forceinline__ void splitf(float f, ushort& h, ushort& l) {
  unsigned int u = __float_as_uint(f);
  h = (ushort)(u >> 16);
  l = f2bf(f - __uint_as_float(u & 0xffff0000u));
}
__device__ __forceinline__ unsigned int cvtpk(float a, float b) {
  unsigned int r;
  asm("v_cvt_pk_bf16_f32 %0, %1, %2" : "=v"(r) : "v"(a), "v"(b));
  return r;
}

__device__ __forceinline__ void gload16(const ushort* g, ushort* l) {
  __builtin_amdgcn_global_load_lds(
      (const __attribute__((address_space(1))) unsigned int*)g,
      (__attribute__((address_space(3))) unsigned int*)l, 16, 0, 0);
}

// ---------------- RoPE cos/sin table ----------------
__global__ __launch_bounds__(256) void rope_table_kernel(float* __restrict__ cosT,
                                                         float* __restrict__ sinT) {
  int idx = blockIdx.x * 256 + threadIdx.x;
  int t = idx >> 6, j = idx & 63;
  float expo = (float)(2 * j) / 128.0f;
  float inv = 1.0f / powf(10000.0f, expo);
  float f = (float)t * inv;
  cosT[idx] = cosf(f);
  sinT[idx] = sinf(f);
}

// ---------------- fp32 -> bf16 hi/lo split ----------------
__global__ __launch_bounds__(256) void split_kernel(const float* __restrict__ in,
                                                    ushort* __restrict__ hi,
                                                    ushort* __restrict__ lo) {
  int i = (blockIdx.x * 256 + threadIdx.x) * 4;
  float4 v = *reinterpret_cast<const float4*>(&in[i]);
  ushort4 h, l;
  splitf(v.x, h.x, l.x);
  splitf(v.y, h.y, l.y);
  splitf(v.z, h.z, l.z);
  splitf(v.w, h.w, l.w);
  *reinterpret_cast<ushort4*>(&hi[i]) = h;
  *reinterpret_cast<ushort4*>(&lo[i]) = l;
}

// ---------------- fp32 -> bf16 (RNE) convert ----------------
__global__ __launch_bounds__(256) void convert_kernel(const float* __restrict__ in,
                                                      ushort* __restrict__ hi) {
  int i = (blockIdx.x * 256 + threadIdx.x) * 4;
  float4 v = *reinterpret_cast<const float4*>(&in[i]);
  ushort4 h;
  h.x = f2bf(v.x); h.y = f2bf(v.y); h.z = f2bf(v.z); h.w = f2bf(v.w);
  *reinterpret_cast<ushort4*>(&hi[i]) = h;
}

// ---------------- 1-term bf16 GEMM: C = Ah * Bh^T ----------------
__global__ __launch_bounds__(256) void gemm1(const ushort* __restrict__ Ah_,
                                             const ushort* __restrict__ Bh_,
                                             ushort* __restrict__ Cout,
                                             int M, int N, int K) {
  __shared__ __align__(16) ushort sAh[128 * 32], sBh[128 * 32];
  const int tid = threadIdx.x;
  const int wave = tid >> 6, lane = tid & 63;
  const int lg = lane >> 4, lm = lane & 15;
  const int nwg = gridDim.x * gridDim.y;
  const int id = blockIdx.y * gridDim.x + blockIdx.x;
  const int cpx = nwg >> 3;
  const int swz = (id & 7) * cpx + (id >> 3);
  const int nbx = N >> 7;
  const int m0 = (swz / nbx) * 128, n0 = (swz % nbx) * 128;
  const int wm = (wave >> 1) * 64, wn = (wave & 1) * 64;
  f32x4 acc[4][4] = {};

  for (int k0 = 0; k0 < K; k0 += 32) {
    __syncthreads();
#pragma unroll
    for (int t = 0; t < 2; ++t) {
      int r = wave * 32 + t * 16 + (lane >> 2);
      int ca = (lane & 3) ^ ((r >> 1) & 3);
      size_t ga = (size_t)(m0 + r) * K + k0 + ca * 8;
      size_t gb = (size_t)(n0 + r) * K + k0 + ca * 8;
      int lb = (wave * 32 + t * 16) * 32;
      gload16(&Ah_[ga], &sAh[lb]);
      gload16(&Bh_[gb], &sBh[lb]);
    }
    __syncthreads();
    bf16x8 ah[4], bh[4];
#pragma unroll
    for (int t = 0; t < 4; ++t) {
      int Ra = wm + t * 16 + lm;
      int Rb = wn + t * 16 + lm;
      int ca = (lg ^ ((Ra >> 1) & 3)) * 8;
      int cb = (lg ^ ((Rb >> 1) & 3)) * 8;
      ah[t] = *reinterpret_cast<const bf16x8*>(&sAh[Ra * 32 + ca]);
      bh[t] = *reinterpret_cast<const bf16x8*>(&sBh[Rb * 32 + cb]);
    }
#pragma unroll
    for (int mi = 0; mi < 4; ++mi)
#pragma unroll
      for (int ni = 0; ni < 4; ++ni)
        acc[mi][ni] = __builtin_amdgcn_mfma_f32_16x16x32_bf16(ah[mi], bh[ni], acc[mi][ni], 0, 0, 0);
  }
#pragma unroll
  for (int mi = 0; mi < 4; ++mi)
#pragma unroll
    for (int ni = 0; ni < 4; ++ni)
#pragma unroll
      for (int j = 0; j < 4; ++j) {
        int row = m0 + wm + mi * 16 + lg * 4 + j;
        int col = n0 + wn + ni * 16 + lm;
        Cout[(size_t)row * N + col] = f2bf(acc[mi][ni][j]);
      }
}

// ---------------- 3-term bf16 GEMM (Wo, f32 out) ----------------
__global__ __launch_bounds__(256) void gemm3(const ushort* __restrict__ Ah_,
                                             const ushort* __restrict__ Al_,
                                             const ushort* __restrict__ Bh_,
                                             const ushort* __restrict__ Bl_,
                                             float* __restrict__ Cout,
                                             int M, int N, int K) {
  __shared__ __align__(16) ushort sAh[128 * 32], sAl[128 * 32], sBh[128 * 32], sBl[128 * 32];
  const int tid = threadIdx.x;
  const int wave = tid >> 6, lane = tid & 63;
  const int lg = lane >> 4, lm = lane & 15;
  const int nwg = gridDim.x * gridDim.y;
  const int id = blockIdx.y * gridDim.x + blockIdx.x;
  const int cpx = nwg >> 3;
  const int swz = (id & 7) * cpx + (id >> 3);
  const int nbx = N >> 7;
  const int m0 = (swz / nbx) * 128, n0 = (swz % nbx) * 128;
  const int wm = (wave >> 1) * 64, wn = (wave & 1) * 64;
  f32x4 acc[4][4] = {};

  for (int k0 = 0; k0 < K; k0 += 32) {
    __syncthreads();
#pragma unroll
    for (int t = 0; t < 2; ++t) {
      int r = wave * 32 + t * 16 + (lane >> 2);
      int ca = (lane & 3) ^ ((r >> 1) & 3);
      size_t ga = (size_t)(m0 + r) * K + k0 + ca * 8;
      size_t gb = (size_t)(n0 + r) * K + k0 + ca * 8;
      int lb = (wave * 32 + t * 16) * 32;
      gload16(&Ah_[ga], &sAh[lb]);
      gload16(&Al_[ga], &sAl[lb]);
      gload16(&Bh_[gb], &sBh[lb]);
      gload16(&Bl_[gb], &sBl[lb]);
    }
    __syncthreads();
    bf16x8 ah[4], al[4], bh[4], bl[4];
#pragma unroll
    for (int t = 0; t < 4; ++t) {
      int Ra = wm + t * 16 + lm;
      int Rb = wn + t * 16 + lm;
      int ca = (lg ^ ((Ra >> 1) & 3)) * 8;
      int cb = (lg ^ ((Rb >> 1) & 3)) * 8;
      ah[t] = *reinterpret_cast<const bf16x8*>(&sAh[Ra * 32 + ca]);
      al[t] = *reinterpret_cast<const bf16x8*>(&sAl[Ra * 32 + ca]);
      bh[t] = *reinterpret_cast<const bf16x8*>(&sBh[Rb * 32 + cb]);
      bl[t] = *reinterpret_cast<const bf16x8*>(&sBl[Rb * 32 + cb]);
    }
#pragma unroll
    for (int mi = 0; mi < 4; ++mi)
#pragma unroll
      for (int ni = 0; ni < 4; ++ni) {
        acc[mi][ni] = __builtin_amdgcn_mfma_f32_16x16x32_bf16(ah[mi], bh[ni], acc[mi][ni], 0, 0, 0);
        acc[mi][ni] = __builtin_amdgcn_mfma_f32_16x16x32_bf16(ah[mi], bl[ni], acc[mi][ni], 0, 0, 0);
        acc[mi][ni] = __builtin_amdgcn_mfma_f32_16x16x32_bf16(al[mi], bh[ni], acc[mi][ni], 0, 0, 0);
      }
  }
#pragma unroll
  for (int mi = 0; mi < 4; ++mi)
#pragma unroll
    for (int ni = 0; ni < 4; ++ni)
#pragma unroll
      for (int j = 0; j < 4; ++j) {
        int row = m0 + wm + mi * 16 + lg * 4 + j;
        int col = n0 + wn + ni * 16 + lm;
        Cout[(size_t)row * N + col] = acc[mi][ni][j];
      }
}

// ---------------- RoPE in-place on Q (scaled 1/sqrt(HD)) and K ----------------
__global__ __launch_bounds__(256) void rope2_kernel(ushort* __restrict__ Q,
                                                    ushort* __restrict__ K,
                                                    const int* __restrict__ pos,
                                                    const float* __restrict__ cosT,
                                                    const float* __restrict__ sinT) {
  int idx = blockIdx.x * 256 + threadIdx.x;
  int s = idx >> 10, dh = idx & 1023;
  int hh = dh >> 6, j = dh & 63;
  int p = pos[s];
  float cs = cosT[p * 64 + j], sn = sinT[p * 64 + j];
  size_t i1 = (size_t)s * DMODEL + hh * HEADDIM + j, i2 = i1 + 64;
  float q1 = bf2f(Q[i1]), q2 = bf2f(Q[i2]);
  float k1 = bf2f(K[i1]), k2 = bf2f(K[i2]);
  const float scl = 0.08838834764831845f;
  Q[i1] = f2bf((q1 * cs - q2 * sn) * scl);
  Q[i2] = f2bf((q2 * cs + q1 * sn) * scl);
  K[i1] = f2bf(k1 * cs - k2 * sn);
  K[i2] = f2bf(k2 * cs + k1 * sn);
}

// ---------------- V transpose ----------------
__global__ __launch_bounds__(256) void transpose_kernel(const ushort* __restrict__ Vr,
                                                        ushort* __restrict__ Vt) {
  __shared__ __align__(16) ushort tile[64 * 72];
  int tid = threadIdx.x;
  int s0 = blockIdx.x * 64, c0 = blockIdx.y * 64;
#pragma unroll
  for (int it = 0; it < 2; ++it) {
    int i = tid + it * 256;
    int r = i >> 3, c = i & 7;
    *reinterpret_cast<uint4*>(&tile[r * 72 + c * 8]) =
        *reinterpret_cast<const uint4*>(&Vr[(size_t)(s0 + r) * DMODEL + c0 + c * 8]);
  }
  __syncthreads();
#pragma unroll
  for (int it = 0; it < 2; ++it) {
    int i = tid + it * 256;
    int cr = i >> 3, sc = i & 7;
    ushort tmp[8];
#pragma unroll
    for (int j = 0; j < 8; ++j) tmp[j] = tile[(sc * 8 + j) * 72 + cr];
    *reinterpret_cast<uint4*>(&Vt[(size_t)(c0 + cr) * S_LEN + s0 + sc * 8]) =
        *reinterpret_cast<uint4*>(tmp);
  }
}

// ---------------- Flash attention v7: v6 + ones-MFMA row-sum + max3 reduce ----------------
__global__ __launch_bounds__(256, 2) void flash7_kernel(const ushort* __restrict__ Q,
                                                        const ushort* __restrict__ Kb,
                                                        const ushort* __restrict__ Vt,
                                                        ushort* __restrict__ Oh,
                                                        ushort* __restrict__ Ol) {
  __shared__ __align__(16) ushort Kt[2][64 * 128];
  __shared__ __align__(16) ushort Vs[2][128 * 64];
  const int tid = threadIdx.x;             // 0..255
  const int wave = tid >> 6, lane = tid & 63;
  const int lg = lane >> 4, lm = lane & 15;
  const int id = blockIdx.y * gridDim.x + blockIdx.x;  // 0..511
  const int o = (id & 7) * 64 + (id >> 3);             // XCD swizzle (512 = 8*64)
  const int h = o >> 5;
  const int q0 = (o & 31) * 128;

  bf16x8 qh[2][4];
#pragma unroll
  for (int t2 = 0; t2 < 2; ++t2) {
    int qrow = q0 + wave * 32 + t2 * 16 + lm;
#pragma unroll
    for (int kc = 0; kc < 4; ++kc)
      qh[t2][kc] = *reinterpret_cast<const bf16x8*>(
          &Q[(size_t)qrow * DMODEL + h * HEADDIM + kc * 32 + lg * 8]);
  }

  bf16x8 ones;
#pragma unroll
  for (int i = 0; i < 8; ++i) ones[i] = (short)0x3f80;  // bf16 1.0

  auto rho = [](int s) {
    return 32 * ((s >> 4) & 1) + 8 * ((s >> 2) & 3) + 4 * (s >> 5) + (s & 3);
  };
  const ushort* pK[4];
  const ushort* pV[4];
  int lbs[4];
#pragma unroll
  for (int k = 0; k < 4; ++k) {
    int ci = k * 256 + wave * 64 + lane;
    int ks = ci >> 4;
    int kcc = (ci & 15) ^ (ks & 7);
    pK[k] = Kb + (size_t)rho(ks) * DMODEL + h * HEADDIM + kcc * 8;
    int vd = ci >> 3;
    int vcc = (ci & 7) ^ (vd & 7);
    pV[k] = Vt + (size_t)(h * HEADDIM + vd) * S_LEN + vcc * 8;
    lbs[k] = (k * 256 + wave * 64) * 8;
  }

  f32x4 oacc[2][8] = {};
  f32x4 osum[2] = {};
  float mrun[2];
#pragma unroll
  for (int t2 = 0; t2 < 2; ++t2) mrun[t2] = -3.0e38f;

#pragma unroll
  for (int k = 0; k < 4; ++k) {
    gload16(pK[k], &Kt[0][lbs[k]]);
    gload16(pV[k], &Vs[0][lbs[k]]);
  }
  __syncthreads();

  for (int t = 0; t < S_LEN / 64; ++t) {
    const int cur = t & 1;
    if (t < S_LEN / 64 - 1) {
      const size_t koff = (size_t)(t + 1) * 64;
#pragma unroll
      for (int k = 0; k < 4; ++k) {
        gload16(pK[k] + koff * DMODEL, &Kt[cur ^ 1][lbs[k]]);
        gload16(pV[k] + koff, &Vs[cur ^ 1][lbs[k]]);
      }
    }
    const ushort* Kc = &Kt[cur][0];
    const ushort* Vc = &Vs[cur][0];

    // QK^T swapped
    f32x4 st[2][4] = {};
    __builtin_amdgcn_s_setprio(1);
#pragma unroll
    for (int nf = 0; nf < 4; ++nf)
#pragma unroll
      for (int kc = 0; kc < 4; ++kc) {
        int pc = (kc * 4 + lg) ^ (lm & 7);
        bf16x8 kfrag = *reinterpret_cast<const bf16x8*>(&Kc[(nf * 16 + lm) * 128 + pc * 8]);
        st[0][nf] = __builtin_amdgcn_mfma_f32_16x16x32_bf16(kfrag, qh[0][kc], st[0][nf], 0, 0, 0);
        st[1][nf] = __builtin_amdgcn_mfma_f32_16x16x32_bf16(kfrag, qh[1][kc], st[1][nf], 0, 0, 0);
      }
    __builtin_amdgcn_s_setprio(0);

    // row max: max3-friendly tree over 16 in-lane values, then cross-half reduce
    float m16[2];
#pragma unroll
    for (int t2 = 0; t2 < 2; ++t2) {
      float m = fmaxf(st[t2][0][0], st[t2][0][1]);
      m = fmaxf(fmaxf(m, st[t2][0][2]), st[t2][0][3]);
      m = fmaxf(fmaxf(m, st[t2][1][0]), st[t2][1][1]);
      m = fmaxf(fmaxf(m, st[t2][1][2]), st[t2][1][3]);
      m = fmaxf(fmaxf(m, st[t2][2][0]), st[t2][2][1]);
      m = fmaxf(fmaxf(m, st[t2][2][2]), st[t2][2][3]);
      m = fmaxf(fmaxf(m, st[t2][3][0]), st[t2][3][1]);
      m = fmaxf(fmaxf(m, st[t2][3][2]), st[t2][3][3]);
      m = fmaxf(m, __shfl_xor(m, 16));
      m = fmaxf(m, __shfl_xor(m, 32));
      m16[t2] = m;
    }

    // defer-max rescale (row-layout scale for oacc AND osum)
    bool grow = (m16[0] > mrun[0] + 8.0f) || (m16[1] > mrun[1] + 8.0f);
    if (__any(grow)) {
#pragma unroll
      for (int t2 = 0; t2 < 2; ++t2) {
        float mn = fmaxf(mrun[t2], m16[t2]);
        float scl = __expf(mrun[t2] - mn);
        mrun[t2] = mn;
        float sj[4];
#pragma unroll
        for (int j = 0; j < 4; ++j) sj[j] = __shfl(scl, lg * 4 + j);
#pragma unroll
        for (int j = 0; j < 4; ++j) osum[t2][j] *= sj[j];
#pragma unroll
        for (int nb = 0; nb < 8; ++nb)
#pragma unroll
          for (int j = 0; j < 4; ++j) oacc[t2][nb][j] *= sj[j];
      }
    }

    // P = exp(S - m) in place (no in-lane sum; sum via ones-MFMA below)
#pragma unroll
    for (int t2 = 0; t2 < 2; ++t2)
#pragma unroll
      for (int nf = 0; nf < 4; ++nf)
#pragma unroll
        for (int j = 0; j < 4; ++j)
          st[t2][nf][j] = __expf(st[t2][nf][j] - mrun[t2]);

    // pack PV A-frags
    bf16x8 pa[2][2];
#pragma unroll
    for (int t2 = 0; t2 < 2; ++t2)
#pragma unroll
      for (int kk = 0; kk < 2; ++kk) {
        union { unsigned int u[4]; bf16x8 v; } w_;
        w_.u[0] = cvtpk(st[t2][kk][0], st[t2][kk][1]);
        w_.u[1] = cvtpk(st[t2][kk][2], st[t2][kk][3]);
        w_.u[2] = cvtpk(st[t2][2 + kk][0], st[t2][2 + kk][1]);
        w_.u[3] = cvtpk(st[t2][2 + kk][2], st[t2][2 + kk][3]);
        pa[t2][kk] = w_.v;
      }

    // PV + row-sum via ones-MFMA (osum in same C-row-layout as oacc)
    __builtin_amdgcn_s_setprio(1);
#pragma unroll
    for (int t2 = 0; t2 < 2; ++t2) {
      osum[t2] = __builtin_amdgcn_mfma_f32_16x16x32_bf16(pa[t2][0], ones, osum[t2], 0, 0, 0);
      osum[t2] = __builtin_amdgcn_mfma_f32_16x16x32_bf16(pa[t2][1], ones, osum[t2], 0, 0, 0);
    }
#pragma unroll
    for (int nb = 0; nb < 8; ++nb)
#pragma unroll
      for (int kk = 0; kk < 2; ++kk) {
        int pc = (kk * 4 + lg) ^ (lm & 7);
        bf16x8 vfrag = *reinterpret_cast<const bf16x8*>(&Vc[(nb * 16 + lm) * 64 + pc * 8]);
        oacc[0][nb] = __builtin_amdgcn_mfma_f32_16x16x32_bf16(pa[0][kk], vfrag, oacc[0][nb], 0, 0, 0);
        oacc[1][nb] = __builtin_amdgcn_mfma_f32_16x16x32_bf16(pa[1][kk], vfrag, oacc[1][nb], 0, 0, 0);
      }
    __builtin_amdgcn_s_setprio(0);

    __syncthreads();
  }

  // epilogue: osum already in row-layout -> no shfl
#pragma unroll
  for (int t2 = 0; t2 < 2; ++t2) {
    float linv[4];
#pragma unroll
    for (int j = 0; j < 4; ++j) linv[j] = 1.0f / osum[t2][j];
#pragma unroll
    for (int nb = 0; nb < 8; ++nb)
#pragma unroll
      for (int j = 0; j < 4; ++j) {
        int row = q0 + wave * 32 + t2 * 16 + lg * 4 + j;
        int col = h * HEADDIM + nb * 16 + lm;
        float ov = oacc[t2][nb][j] * linv[j];
        ushort hi, lo;
        splitf(ov, hi, lo);
        Oh[(size_t)row * DMODEL + col] = hi;
        Ol[(size_t)row * DMODEL + col] = lo;
      }
  }
}

extern "C" void kernel_launch(void* const* d_in, const int* in_sizes, int n_in,
                              void* d_out, int out_size, void* d_ws, size_t ws_size,
                              hipStream_t stream) {
  (void)in_sizes; (void)n_in; (void)out_size; (void)ws_size;
  const float* X  = (const float*)d_in[0];
  const float* Wq = (const float*)d_in[1];
  const float* Wk = (const float*)d_in[2];
  const float* Wv = (const float*)d_in[3];
  const float* Wo = (const float*)d_in[4];
  const int* pos  = (const int*)d_in[5];
  float* out = (float*)d_out;

  ushort* wb = (ushort*)d_ws;
  const size_t SD = (size_t)S_LEN * DMODEL;       // 8388608 elements
  const size_t DD = (size_t)DMODEL * DMODEL;      // 4194304 elements

  ushort* Xh  = wb;              // slot0
  ushort* OlB = wb + SD;         // slot1 (free until flash)
  ushort* Qr  = wb + 2 * SD;     // slot2
  ushort* Kr  = wb + 3 * SD;     // slot3
  ushort* Vr  = wb + 4 * SD;     // slot4: later Oh
  ushort* Vt  = wb + 5 * SD;     // slot5
  ushort* W0h = wb + 6 * SD;     // Wo hi
  ushort* W0l = wb + 6 * SD + DD;  // Wo lo
  ushort* Wqh = wb + 7 * SD;
  ushort* Wkh = wb + 7 * SD + DD;
  ushort* Wvh = wb + 8 * SD;
  float* cosT = (float*)(wb + 9 * SD);
  float* sinT = cosT + (size_t)S_LEN * 64;
  ushort* OhB = Vr;  // reuse after transpose

  rope_table_kernel<<<S_LEN * 64 / 256, 256, 0, stream>>>(cosT, sinT);
  convert_kernel<<<SD / 1024, 256, 0, stream>>>(X, Xh);
  convert_kernel<<<DD / 1024, 256, 0, stream>>>(Wq, Wqh);
  convert_kernel<<<DD / 1024, 256, 0, stream>>>(Wk, Wkh);
  convert_kernel<<<DD / 1024, 256, 0, stream>>>(Wv, Wvh);
  split_kernel<<<DD / 1024, 256, 0, stream>>>(Wo, W0h, W0l);

  dim3 gemmGrid(DMODEL / 128, S_LEN / 128);
  gemm1<<<gemmGrid, 256, 0, stream>>>(Xh, Wqh, Qr, S_LEN, DMODEL, DMODEL);
  gemm1<<<gemmGrid, 256, 0, stream>>>(Xh, Wkh, Kr, S_LEN, DMODEL, DMODEL);
  gemm1<<<gemmGrid, 256, 0, stream>>>(Xh, Wvh, Vr, S_LEN, DMODEL, DMODEL);

  rope2_kernel<<<(S_LEN * 1024) / 256, 256, 0, stream>>>(Qr, Kr, pos, cosT, sinT);
  transpose_kernel<<<dim3(S_LEN / 64, DMODEL / 64), 256, 0, stream>>>(Vr, Vt);

  flash7_kernel<<<dim3(32, 16), 256, 0, stream>>>(Qr, Kr, Vt, OhB, OlB);

  gemm3<<<gemmGrid, 256, 0, stream>>>(OhB, OlB, W0h, W0l, out, S_LEN, DMODEL, DMODEL);
}